// Round 3
// baseline (415.520 us; speedup 1.0000x reference)
//
#include <hip/hip_runtime.h>
#include <math.h>

#define B 8
#define N 8192
#define S 2048
#define C 256
#define CIN 512
#define CNT (B * N)  // 65536

typedef __attribute__((ext_vector_type(8))) short bf16x8;
typedef __attribute__((ext_vector_type(4))) float floatx4;
typedef __attribute__((ext_vector_type(8))) unsigned short ushort8v;
typedef __attribute__((ext_vector_type(4))) unsigned short ushort4v;

__device__ inline unsigned short f2bf(float f) {
  unsigned u = __builtin_bit_cast(unsigned, f);
  u += 0x7FFF + ((u >> 16) & 1);  // RNE
  return (unsigned short)(u >> 16);
}
__device__ inline float bf2f(unsigned short h) {
  unsigned u = ((unsigned)h) << 16;
  return __builtin_bit_cast(float, u);
}

__device__ inline void load_lds16(const void* g, void* l) {
  __builtin_amdgcn_global_load_lds(
      (const __attribute__((address_space(1))) unsigned int*)g,
      (__attribute__((address_space(3))) unsigned int*)l, 16, 0, 0);
}

// ---------------- 3-NN v4: u64 (dist|idx) keys, 8 sub-threads/query ----------------
__device__ inline void ins3u(unsigned long long k, unsigned long long& k0,
                             unsigned long long& k1, unsigned long long& k2) {
  if (k < k2) {
    if (k < k1) {
      k2 = k1;
      if (k < k0) { k1 = k0; k0 = k; } else k1 = k;
    } else k2 = k;
  }
}

__global__ __launch_bounds__(256) void nn3_kernel(const float* __restrict__ xyz1,
                                                  const float* __restrict__ xyz2,
                                                  int* __restrict__ idxbuf,
                                                  float* __restrict__ wbuf) {
  __shared__ float4 sp[S];  // {x,y,z,|p|^2 + 1}  32KB
  int b = blockIdx.x >> 8;            // grid = B * (N/32) = 2048
  int n0 = (blockIdx.x & 255) * 32;
  const float* p2 = xyz2 + (size_t)b * 3 * S;
  for (int i = threadIdx.x; i < S; i += 256) {
    float px = p2[i], py = p2[S + i], pz = p2[2 * S + i];
    sp[i] = make_float4(px, py, pz, px * px + py * py + pz * pz + 1.0f);
  }
  __syncthreads();
  int tid = threadIdx.x;
  int nl = tid >> 3, sub = tid & 7;   // 32 queries/block, 8 subs/query
  int n = n0 + nl;
  const float* p1 = xyz1 + (size_t)b * 3 * N;
  float ox = p1[n], oy = p1[N + n], oz = p1[2 * N + n];
  float q2 = ox * ox + oy * oy + oz * oz;
  float qx = -2.0f * ox, qy = -2.0f * oy, qz = -2.0f * oz;
  // key = (float_bits(dist + 1) << 32) | s  — dist+1 > 0 so uint order == float order;
  // low word = index gives top_k's smallest-index tie-break for free.
  unsigned long long k0 = ~0ull, k1 = ~0ull, k2 = ~0ull;
#pragma unroll 8
  for (int t = 0; t < S / 8; ++t) {
    int s = t * 8 + sub;              // bank-interleaved: 8 subs hit 8 distinct bank quads
    float4 p = sp[s];
    float d = fmaf(qx, p.x, fmaf(qy, p.y, fmaf(qz, p.z, p.w))) + q2;
    unsigned long long key = ((unsigned long long)__float_as_uint(d) << 32) | (unsigned)s;
    if (key < k2) {
      if (key < k1) {
        k2 = k1;
        if (key < k0) { k1 = k0; k0 = key; } else k1 = key;
      } else k2 = key;
    }
  }
  // merge the 8 sub-scans (xor butterfly within each 8-lane group)
#pragma unroll
  for (int m = 1; m <= 4; m <<= 1) {
    unsigned long long e0 = (unsigned long long)__shfl_xor((long long)k0, m);
    unsigned long long e1 = (unsigned long long)__shfl_xor((long long)k1, m);
    unsigned long long e2 = (unsigned long long)__shfl_xor((long long)k2, m);
    ins3u(e0, k0, k1, k2);
    ins3u(e1, k0, k1, k2);
    ins3u(e2, k0, k1, k2);
  }
  if (sub == 0) {
    float d0 = __uint_as_float((unsigned)(k0 >> 32)) - 1.0f;
    float d1 = __uint_as_float((unsigned)(k1 >> 32)) - 1.0f;
    float d2 = __uint_as_float((unsigned)(k2 >> 32)) - 1.0f;
    float r0 = 1.0f / (d0 + 1e-8f);
    float r1 = 1.0f / (d1 + 1e-8f);
    float r2 = 1.0f / (d2 + 1e-8f);
    float rs = 1.0f / (r0 + r1 + r2);
    size_t o = ((size_t)b * N + n) * 3;
    idxbuf[o] = (int)(unsigned)k0;
    idxbuf[o + 1] = (int)(unsigned)k1;
    idxbuf[o + 2] = (int)(unsigned)k2;
    wbuf[o] = r0 * rs; wbuf[o + 1] = r1 * rs; wbuf[o + 2] = r2 * rs;
  }
}

// ---------------- weights f32 -> bf16 ----------------
__global__ __launch_bounds__(256) void convw_kernel(const float* __restrict__ w0,
                                                    const float* __restrict__ w1,
                                                    unsigned short* __restrict__ w0b,
                                                    unsigned short* __restrict__ w1b) {
  int i = blockIdx.x * 256 + threadIdx.x;
  if (i < C * CIN) w0b[i] = f2bf(w0[i]);
  else {
    int j = i - C * CIN;
    if (j < C * C) w1b[j] = f2bf(w1[j]);
  }
}

// ---------------- transpose+convert: src[b][256][cols] f32 -> dst[b][cols][drow] bf16 ----------------
__global__ __launch_bounds__(256) void tconv_kernel(const float* __restrict__ src,
                                                    unsigned short* __restrict__ dst,
                                                    int cols, int drow, int coff) {
  __shared__ float t[64][65];
  int n0 = blockIdx.x * 64, c0 = blockIdx.y * 64, b = blockIdx.z;
  int tid = threadIdx.x, r = tid >> 2, q = tid & 3;
  const float* sp = src + ((size_t)b * 256 + c0 + r) * cols + n0 + q * 16;
#pragma unroll
  for (int i = 0; i < 4; ++i) {
    float4 v = *(const float4*)(sp + i * 4);
    t[r][q * 16 + i * 4 + 0] = v.x;
    t[r][q * 16 + i * 4 + 1] = v.y;
    t[r][q * 16 + i * 4 + 2] = v.z;
    t[r][q * 16 + i * 4 + 3] = v.w;
  }
  __syncthreads();
  unsigned short* dp = dst + ((size_t)b * cols + n0 + r) * drow + coff + c0 + q * 16;
  ushort8v o0, o1;
#pragma unroll
  for (int i = 0; i < 8; ++i) o0[i] = f2bf(t[q * 16 + i][r]);
#pragma unroll
  for (int i = 0; i < 8; ++i) o1[i] = f2bf(t[q * 16 + 8 + i][r]);
  *(ushort8v*)dp = o0;
  *(ushort8v*)(dp + 8) = o1;
}

// ---------------- gather: Xb[b][n][256+c] = sum_j w_j * p2t[b][idx_j][c] ----------------
__global__ __launch_bounds__(256) void gather_kernel(const unsigned short* __restrict__ p2t,
                                                     const int* __restrict__ idxbuf,
                                                     const float* __restrict__ wbuf,
                                                     unsigned short* __restrict__ Xb) {
  __shared__ int si[192];
  __shared__ float sw[192];
  int b = blockIdx.x >> 7;  // grid = B * (N/64)
  int n0 = (blockIdx.x & 127) * 64;
  size_t base = ((size_t)b * N + n0) * 3;
  if (threadIdx.x < 192) {
    si[threadIdx.x] = idxbuf[base + threadIdx.x];
    sw[threadIdx.x] = wbuf[base + threadIdx.x];
  }
  __syncthreads();
  int nl = threadIdx.x >> 2, cb = threadIdx.x & 3;
  int j0 = si[nl * 3], j1 = si[nl * 3 + 1], j2 = si[nl * 3 + 2];
  float w0 = sw[nl * 3], w1 = sw[nl * 3 + 1], w2 = sw[nl * 3 + 2];
  const unsigned short* pb = p2t + (size_t)b * S * 256;
  const unsigned short* r0p = pb + (size_t)j0 * 256;
  const unsigned short* r1p = pb + (size_t)j1 * 256;
  const unsigned short* r2p = pb + (size_t)j2 * 256;
  unsigned short* xp = Xb + ((size_t)b * N + n0 + nl) * 512 + 256;
#pragma unroll
  for (int ch = 0; ch < 8; ++ch) {
    int co = (cb + ch * 4) * 8;
    ushort8v v0 = *(const ushort8v*)(r0p + co);
    ushort8v v1 = *(const ushort8v*)(r1p + co);
    ushort8v v2 = *(const ushort8v*)(r2p + co);
    ushort8v o;
#pragma unroll
    for (int i = 0; i < 8; ++i)
      o[i] = f2bf(w0 * bf2f(v0[i]) + w1 * bf2f(v1[i]) + w2 * bf2f(v2[i]));
    *(ushort8v*)(xp + co) = o;
  }
}

// ---------------- bf16 MFMA GEMM + fused per-channel stats ----------------
// Y[b][n][o] = bias[o] + sum_k W[o][k] X[b][n][k]; atomically accumulates
// sum_n Y and sum_n Y^2 into sumb/sumsqb (for training-mode BN).
__global__ __launch_bounds__(256) void gemm_kernel(const unsigned short* __restrict__ X,
                                                   const unsigned short* __restrict__ Wb,
                                                   const float* __restrict__ bias,
                                                   unsigned short* __restrict__ Y,
                                                   float* __restrict__ sumb,
                                                   float* __restrict__ sumsqb,
                                                   int Cin) {
  __shared__ unsigned short As[128 * 32];  // [o_row][k] 8KB
  __shared__ unsigned short Bs[128 * 32];  // [n_row][k] 8KB
  int n0 = blockIdx.x * 128, o0 = blockIdx.y * 128, b = blockIdx.z;
  int tid = threadIdx.x, lane = tid & 63, wid = tid >> 6;
  int wm = wid >> 1, wn = wid & 1;
  floatx4 acc[4][4];
#pragma unroll
  for (int m = 0; m < 4; ++m)
#pragma unroll
    for (int nt = 0; nt < 4; ++nt) acc[m][nt] = (floatx4)(0.0f);

  size_t rsA = (size_t)Cin * 2;  // row stride bytes
  const char* Abase = (const char*)Wb + (size_t)(o0 + wid * 32 + (lane >> 2)) * rsA + (lane & 3) * 16;
  const char* Bbase = (const char*)X + ((size_t)b * N + n0 + wid * 32 + (lane >> 2)) * rsA + (lane & 3) * 16;
  size_t rstep16 = 16 * rsA;
  int kq = (lane >> 4) * 8;

  for (int k0 = 0; k0 < Cin; k0 += 32) {
    load_lds16(Abase + (size_t)k0 * 2, &As[(wid * 32) * 32]);
    load_lds16(Abase + (size_t)k0 * 2 + rstep16, &As[(wid * 32 + 16) * 32]);
    load_lds16(Bbase + (size_t)k0 * 2, &Bs[(wid * 32) * 32]);
    load_lds16(Bbase + (size_t)k0 * 2 + rstep16, &Bs[(wid * 32 + 16) * 32]);
    __syncthreads();
    bf16x8 af[4], bfv[4];
#pragma unroll
    for (int m = 0; m < 4; ++m)
      af[m] = *(const bf16x8*)&As[(wm * 64 + m * 16 + (lane & 15)) * 32 + kq];
#pragma unroll
    for (int nt = 0; nt < 4; ++nt)
      bfv[nt] = *(const bf16x8*)&Bs[(wn * 64 + nt * 16 + (lane & 15)) * 32 + kq];
#pragma unroll
    for (int m = 0; m < 4; ++m)
#pragma unroll
      for (int nt = 0; nt < 4; ++nt)
        acc[m][nt] = __builtin_amdgcn_mfma_f32_16x16x32_bf16(af[m], bfv[nt], acc[m][nt], 0, 0, 0);
    __syncthreads();
  }

  int col = lane & 15, rowq = lane >> 4;
#pragma unroll
  for (int m = 0; m < 4; ++m) {
    int ob = o0 + wm * 64 + m * 16 + rowq * 4;
    float4 bs = *(const float4*)&bias[ob];
    float sj[4] = {0.f, 0.f, 0.f, 0.f}, qj[4] = {0.f, 0.f, 0.f, 0.f};
#pragma unroll
    for (int nt = 0; nt < 4; ++nt) {
      int n = n0 + wn * 64 + nt * 16 + col;
      float y0 = acc[m][nt][0] + bs.x;
      float y1 = acc[m][nt][1] + bs.y;
      float y2 = acc[m][nt][2] + bs.z;
      float y3 = acc[m][nt][3] + bs.w;
      ushort4v v;
      v[0] = f2bf(y0); v[1] = f2bf(y1); v[2] = f2bf(y2); v[3] = f2bf(y3);
      *(ushort4v*)&Y[((size_t)b * N + n) * 256 + ob] = v;
      sj[0] += y0; qj[0] = fmaf(y0, y0, qj[0]);
      sj[1] += y1; qj[1] = fmaf(y1, y1, qj[1]);
      sj[2] += y2; qj[2] = fmaf(y2, y2, qj[2]);
      sj[3] += y3; qj[3] = fmaf(y3, y3, qj[3]);
    }
    // reduce over the 16-lane col group (covers this wave's 64 n values)
#pragma unroll
    for (int j = 0; j < 4; ++j) {
#pragma unroll
      for (int d = 1; d <= 8; d <<= 1) {
        sj[j] += __shfl_xor(sj[j], d);
        qj[j] += __shfl_xor(qj[j], d);
      }
    }
    if (col == 0) {
#pragma unroll
      for (int j = 0; j < 4; ++j) {
        atomicAdd(&sumb[ob + j], sj[j]);
        atomicAdd(&sumsqb[ob + j], qj[j]);
      }
    }
  }
}

__global__ void bnparam_kernel(const float* __restrict__ sum, const float* __restrict__ sumsq,
                               const float* __restrict__ gamma, const float* __restrict__ beta,
                               float* __restrict__ scale, float* __restrict__ shift) {
  int c = threadIdx.x;
  float m = sum[c] * (1.0f / CNT);
  float v = sumsq[c] * (1.0f / CNT) - m * m;
  float sc = gamma[c] * rsqrtf(v + 1e-5f);
  scale[c] = sc;
  shift[c] = beta[c] - m * sc;
}

// ---------------- BN+ReLU elementwise on [b][n][256] bf16 -> bf16 ----------------
__global__ __launch_bounds__(256) void bnrelu_kernel(const unsigned short* __restrict__ Y,
                                                     const float* __restrict__ scale,
                                                     const float* __restrict__ shift,
                                                     unsigned short* __restrict__ H) {
  size_t total = (size_t)B * N * 256 / 8;
  for (size_t i = (size_t)blockIdx.x * 256 + threadIdx.x; i < total;
       i += (size_t)gridDim.x * 256) {
    int ob = ((int)i & 31) * 8;
    float4 s0 = *(const float4*)&scale[ob];
    float4 s1 = *(const float4*)&scale[ob + 4];
    float4 h0 = *(const float4*)&shift[ob];
    float4 h1 = *(const float4*)&shift[ob + 4];
    ushort8v v = *(const ushort8v*)&Y[i * 8];
    ushort8v o;
    o[0] = f2bf(fmaxf(fmaf(bf2f(v[0]), s0.x, h0.x), 0.f));
    o[1] = f2bf(fmaxf(fmaf(bf2f(v[1]), s0.y, h0.y), 0.f));
    o[2] = f2bf(fmaxf(fmaf(bf2f(v[2]), s0.z, h0.z), 0.f));
    o[3] = f2bf(fmaxf(fmaf(bf2f(v[3]), s0.w, h0.w), 0.f));
    o[4] = f2bf(fmaxf(fmaf(bf2f(v[4]), s1.x, h1.x), 0.f));
    o[5] = f2bf(fmaxf(fmaf(bf2f(v[5]), s1.y, h1.y), 0.f));
    o[6] = f2bf(fmaxf(fmaf(bf2f(v[6]), s1.z, h1.z), 0.f));
    o[7] = f2bf(fmaxf(fmaf(bf2f(v[7]), s1.w, h1.w), 0.f));
    *(ushort8v*)&H[i * 8] = o;
  }
}

// ---------------- final: BN+ReLU + transpose [b][n][o] bf16 -> out [b][o][n] f32 ----------------
__global__ __launch_bounds__(256) void bnreluT_kernel(const unsigned short* __restrict__ Y,
                                                      const float* __restrict__ scale,
                                                      const float* __restrict__ shift,
                                                      float* __restrict__ out) {
  __shared__ float t[64][65];
  int n0 = blockIdx.x * 64, o0 = blockIdx.y * 64, b = blockIdx.z;
  int tid = threadIdx.x, r = tid >> 2, q = tid & 3;
  const unsigned short* yp = Y + ((size_t)b * N + n0 + r) * 256 + o0 + q * 16;
#pragma unroll
  for (int h = 0; h < 2; ++h) {
    ushort8v v = *(const ushort8v*)(yp + h * 8);
#pragma unroll
    for (int i = 0; i < 8; ++i) {
      int oc = q * 16 + h * 8 + i;
      float f = fmaxf(fmaf(bf2f(v[i]), scale[o0 + oc], shift[o0 + oc]), 0.f);
      t[oc][r] = f;
    }
  }
  __syncthreads();
  float* op = out + ((size_t)b * 256 + o0 + r) * N + n0 + q * 16;
#pragma unroll
  for (int i = 0; i < 4; ++i) {
    float4 v = make_float4(t[r][q * 16 + i * 4 + 0], t[r][q * 16 + i * 4 + 1],
                           t[r][q * 16 + i * 4 + 2], t[r][q * 16 + i * 4 + 3]);
    *(float4*)(op + i * 4) = v;
  }
}

extern "C" void kernel_launch(void* const* d_in, const int* in_sizes, int n_in,
                              void* d_out, int out_size, void* d_ws, size_t ws_size,
                              hipStream_t stream) {
  const float* xyz1 = (const float*)d_in[0];
  const float* xyz2 = (const float*)d_in[1];
  const float* points1 = (const float*)d_in[2];
  const float* points2 = (const float*)d_in[3];
  const float* w0 = (const float*)d_in[4];
  const float* b0 = (const float*)d_in[5];
  const float* g0 = (const float*)d_in[6];
  const float* be0 = (const float*)d_in[7];
  const float* w1 = (const float*)d_in[8];
  const float* b1 = (const float*)d_in[9];
  const float* g1 = (const float*)d_in[10];
  const float* be1 = (const float*)d_in[11];
  float* out = (float*)d_out;

  char* ws = (char*)d_ws;
  int* idxbuf = (int*)ws;              ws += (size_t)CNT * 3 * 4;      // 768KB
  float* wbuf = (float*)ws;            ws += (size_t)CNT * 3 * 4;      // 768KB
  float* stats = (float*)ws;           ws += (size_t)8 * 256 * 4;      // 8KB
  float* sum0 = stats, *sumsq0 = stats + 256;
  float* sum1 = stats + 512, *sumsq1 = stats + 768;
  float* scale0 = stats + 1024, *shift0 = stats + 1280;
  float* scale1 = stats + 1536, *shift1 = stats + 1792;
  unsigned short* w0b = (unsigned short*)ws;  ws += (size_t)C * CIN * 2;   // 256KB
  unsigned short* w1b = (unsigned short*)ws;  ws += (size_t)C * C * 2;     // 128KB
  unsigned short* p2t = (unsigned short*)ws;  ws += (size_t)B * S * 256 * 2;   // 8MB
  unsigned short* Xb = (unsigned short*)ws;   ws += (size_t)B * N * 512 * 2;   // 64MB
  unsigned short* Yb = (unsigned short*)ws;   ws += (size_t)B * N * 256 * 2;   // 32MB
  unsigned short* Hb = Xb;  // reuse Xb after GEMM0 consumed it

  hipMemsetAsync(stats, 0, 4 * 256 * 4, stream);
  convw_kernel<<<dim3((C * CIN + C * C) / 256), 256, 0, stream>>>(w0, w1, w0b, w1b);
  tconv_kernel<<<dim3(N / 64, 4, B), 256, 0, stream>>>(points1, Xb, N, 512, 0);
  tconv_kernel<<<dim3(S / 64, 4, B), 256, 0, stream>>>(points2, p2t, S, 256, 0);
  nn3_kernel<<<dim3(B * N / 32), 256, 0, stream>>>(xyz1, xyz2, idxbuf, wbuf);
  gather_kernel<<<dim3(B * N / 64), 256, 0, stream>>>(p2t, idxbuf, wbuf, Xb);
  gemm_kernel<<<dim3(N / 128, 2, B), 256, 0, stream>>>(Xb, w0b, b0, Yb, sum0, sumsq0, CIN);
  bnparam_kernel<<<1, 256, 0, stream>>>(sum0, sumsq0, g0, be0, scale0, shift0);
  bnrelu_kernel<<<dim3(2048), 256, 0, stream>>>(Yb, scale0, shift0, Hb);
  gemm_kernel<<<dim3(N / 128, 2, B), 256, 0, stream>>>(Hb, w1b, b1, Yb, sum1, sumsq1, C);
  bnparam_kernel<<<1, 256, 0, stream>>>(sum1, sumsq1, g1, be1, scale1, shift1);
  bnreluT_kernel<<<dim3(N / 64, 4, B), 256, 0, stream>>>(Yb, scale1, shift1, out);
}

// Round 4
// 253.756 us; speedup vs baseline: 1.6375x; 1.6375x over previous
//
#include <hip/hip_runtime.h>
#include <math.h>

#define B 8
#define N 8192
#define S 2048
#define C 256
#define CIN 512
#define CNT (B * N)  // 65536

typedef __attribute__((ext_vector_type(8))) short bf16x8;
typedef __attribute__((ext_vector_type(4))) float floatx4;
typedef __attribute__((ext_vector_type(8))) unsigned short ushort8v;
typedef __attribute__((ext_vector_type(4))) unsigned short ushort4v;

__device__ inline unsigned short f2bf(float f) {
  unsigned u = __builtin_bit_cast(unsigned, f);
  u += 0x7FFF + ((u >> 16) & 1);  // RNE
  return (unsigned short)(u >> 16);
}
__device__ inline float bf2f(unsigned short h) {
  unsigned u = ((unsigned)h) << 16;
  return __builtin_bit_cast(float, u);
}

__device__ inline void load_lds16(const void* g, void* l) {
  __builtin_amdgcn_global_load_lds(
      (const __attribute__((address_space(1))) unsigned int*)g,
      (__attribute__((address_space(3))) unsigned int*)l, 16, 0, 0);
}

// ---------------- 3-NN: u64 (dist|idx) keys, 8 sub-threads/query ----------------
__device__ inline void ins3u(unsigned long long k, unsigned long long& k0,
                             unsigned long long& k1, unsigned long long& k2) {
  if (k < k2) {
    if (k < k1) {
      k2 = k1;
      if (k < k0) { k1 = k0; k0 = k; } else k1 = k;
    } else k2 = k;
  }
}

__global__ __launch_bounds__(256) void nn3_kernel(const float* __restrict__ xyz1,
                                                  const float* __restrict__ xyz2,
                                                  int* __restrict__ idxbuf,
                                                  float* __restrict__ wbuf) {
  __shared__ float4 sp[S];  // {x,y,z,|p|^2 + 1}  32KB
  int b = blockIdx.x >> 8;            // grid = B * (N/32) = 2048
  int n0 = (blockIdx.x & 255) * 32;
  const float* p2 = xyz2 + (size_t)b * 3 * S;
  for (int i = threadIdx.x; i < S; i += 256) {
    float px = p2[i], py = p2[S + i], pz = p2[2 * S + i];
    sp[i] = make_float4(px, py, pz, px * px + py * py + pz * pz + 1.0f);
  }
  __syncthreads();
  int tid = threadIdx.x;
  int nl = tid >> 3, sub = tid & 7;   // 32 queries/block, 8 subs/query
  int n = n0 + nl;
  const float* p1 = xyz1 + (size_t)b * 3 * N;
  float ox = p1[n], oy = p1[N + n], oz = p1[2 * N + n];
  float q2 = ox * ox + oy * oy + oz * oz;
  float qx = -2.0f * ox, qy = -2.0f * oy, qz = -2.0f * oz;
  unsigned long long k0 = ~0ull, k1 = ~0ull, k2 = ~0ull;
#pragma unroll 8
  for (int t = 0; t < S / 8; ++t) {
    int s = t * 8 + sub;
    float4 p = sp[s];
    float d = fmaf(qx, p.x, fmaf(qy, p.y, fmaf(qz, p.z, p.w))) + q2;
    unsigned long long key = ((unsigned long long)__float_as_uint(d) << 32) | (unsigned)s;
    if (key < k2) {
      if (key < k1) {
        k2 = k1;
        if (key < k0) { k1 = k0; k0 = key; } else k1 = key;
      } else k2 = key;
    }
  }
#pragma unroll
  for (int m = 1; m <= 4; m <<= 1) {
    unsigned long long e0 = (unsigned long long)__shfl_xor((long long)k0, m);
    unsigned long long e1 = (unsigned long long)__shfl_xor((long long)k1, m);
    unsigned long long e2 = (unsigned long long)__shfl_xor((long long)k2, m);
    ins3u(e0, k0, k1, k2);
    ins3u(e1, k0, k1, k2);
    ins3u(e2, k0, k1, k2);
  }
  if (sub == 0) {
    float d0 = __uint_as_float((unsigned)(k0 >> 32)) - 1.0f;
    float d1 = __uint_as_float((unsigned)(k1 >> 32)) - 1.0f;
    float d2 = __uint_as_float((unsigned)(k2 >> 32)) - 1.0f;
    float r0 = 1.0f / (d0 + 1e-8f);
    float r1 = 1.0f / (d1 + 1e-8f);
    float r2 = 1.0f / (d2 + 1e-8f);
    float rs = 1.0f / (r0 + r1 + r2);
    size_t o = ((size_t)b * N + n) * 3;
    idxbuf[o] = (int)(unsigned)k0;
    idxbuf[o + 1] = (int)(unsigned)k1;
    idxbuf[o + 2] = (int)(unsigned)k2;
    wbuf[o] = r0 * rs; wbuf[o + 1] = r1 * rs; wbuf[o + 2] = r2 * rs;
  }
}

// ---------------- weights f32 -> bf16 ----------------
__global__ __launch_bounds__(256) void convw_kernel(const float* __restrict__ w0,
                                                    const float* __restrict__ w1,
                                                    unsigned short* __restrict__ w0b,
                                                    unsigned short* __restrict__ w1b) {
  int i = blockIdx.x * 256 + threadIdx.x;
  if (i < C * CIN) w0b[i] = f2bf(w0[i]);
  else {
    int j = i - C * CIN;
    if (j < C * C) w1b[j] = f2bf(w1[j]);
  }
}

// ---------------- transpose+convert: src[b][256][cols] f32 -> dst[b][cols][drow] bf16 ----------------
__global__ __launch_bounds__(256) void tconv_kernel(const float* __restrict__ src,
                                                    unsigned short* __restrict__ dst,
                                                    int cols, int drow, int coff) {
  __shared__ float t[64][65];
  int n0 = blockIdx.x * 64, c0 = blockIdx.y * 64, b = blockIdx.z;
  int tid = threadIdx.x, r = tid >> 2, q = tid & 3;
  const float* sp = src + ((size_t)b * 256 + c0 + r) * cols + n0 + q * 16;
#pragma unroll
  for (int i = 0; i < 4; ++i) {
    float4 v = *(const float4*)(sp + i * 4);
    t[r][q * 16 + i * 4 + 0] = v.x;
    t[r][q * 16 + i * 4 + 1] = v.y;
    t[r][q * 16 + i * 4 + 2] = v.z;
    t[r][q * 16 + i * 4 + 3] = v.w;
  }
  __syncthreads();
  unsigned short* dp = dst + ((size_t)b * cols + n0 + r) * drow + coff + c0 + q * 16;
  ushort8v o0, o1;
#pragma unroll
  for (int i = 0; i < 8; ++i) o0[i] = f2bf(t[q * 16 + i][r]);
#pragma unroll
  for (int i = 0; i < 8; ++i) o1[i] = f2bf(t[q * 16 + 8 + i][r]);
  *(ushort8v*)dp = o0;
  *(ushort8v*)(dp + 8) = o1;
}

// ---------------- gather: Xb[b][n][256+c] = sum_j w_j * p2t[b][idx_j][c] ----------------
__global__ __launch_bounds__(256) void gather_kernel(const unsigned short* __restrict__ p2t,
                                                     const int* __restrict__ idxbuf,
                                                     const float* __restrict__ wbuf,
                                                     unsigned short* __restrict__ Xb) {
  __shared__ int si[192];
  __shared__ float sw[192];
  int b = blockIdx.x >> 7;  // grid = B * (N/64)
  int n0 = (blockIdx.x & 127) * 64;
  size_t base = ((size_t)b * N + n0) * 3;
  if (threadIdx.x < 192) {
    si[threadIdx.x] = idxbuf[base + threadIdx.x];
    sw[threadIdx.x] = wbuf[base + threadIdx.x];
  }
  __syncthreads();
  int nl = threadIdx.x >> 2, cb = threadIdx.x & 3;
  int j0 = si[nl * 3], j1 = si[nl * 3 + 1], j2 = si[nl * 3 + 2];
  float w0 = sw[nl * 3], w1 = sw[nl * 3 + 1], w2 = sw[nl * 3 + 2];
  const unsigned short* pb = p2t + (size_t)b * S * 256;
  const unsigned short* r0p = pb + (size_t)j0 * 256;
  const unsigned short* r1p = pb + (size_t)j1 * 256;
  const unsigned short* r2p = pb + (size_t)j2 * 256;
  unsigned short* xp = Xb + ((size_t)b * N + n0 + nl) * 512 + 256;
#pragma unroll
  for (int ch = 0; ch < 8; ++ch) {
    int co = (cb + ch * 4) * 8;
    ushort8v v0 = *(const ushort8v*)(r0p + co);
    ushort8v v1 = *(const ushort8v*)(r1p + co);
    ushort8v v2 = *(const ushort8v*)(r2p + co);
    ushort8v o;
#pragma unroll
    for (int i = 0; i < 8; ++i)
      o[i] = f2bf(w0 * bf2f(v0[i]) + w1 * bf2f(v1[i]) + w2 * bf2f(v2[i]));
    *(ushort8v*)(xp + co) = o;
  }
}

// ---------------- bf16 MFMA GEMM: Y[b][n][o] = bias[o] + sum_k W[o][k] X[b][n][k] ----------------
// LDS tiles are XOR-swizzled (T2, rule 21): global_load_lds dest stays LINEAR;
// the 16B chunk index is pre-swizzled on the GLOBAL source (chunk ^= (row>>1)&3,
// period 8 in row -> same per-lane formula for both 16-row halves) and the same
// involution is applied on the ds_read side. Kills the 8-way bank conflict of
// 64B rows (start banks were {0,16} only).
__global__ __launch_bounds__(256) void gemm_kernel(const unsigned short* __restrict__ X,
                                                   const unsigned short* __restrict__ Wb,
                                                   const float* __restrict__ bias,
                                                   unsigned short* __restrict__ Y,
                                                   int Cin) {
  __shared__ unsigned short As[128 * 32];  // [o_row][k] 8KB, swizzled
  __shared__ unsigned short Bs[128 * 32];  // [n_row][k] 8KB, swizzled
  int n0 = blockIdx.x * 128, o0 = blockIdx.y * 128, b = blockIdx.z;
  int tid = threadIdx.x, lane = tid & 63, wid = tid >> 6;
  int wm = wid >> 1, wn = wid & 1;
  floatx4 acc[4][4];
#pragma unroll
  for (int m = 0; m < 4; ++m)
#pragma unroll
    for (int nt = 0; nt < 4; ++nt) acc[m][nt] = (floatx4)(0.0f);

  size_t rsA = (size_t)Cin * 2;  // row stride bytes
  // staging source: row = base + lane>>2, chunk = (lane&3) ^ ((lane>>3)&3)
  int chunkSwz = ((lane & 3) ^ ((lane >> 3) & 3)) * 16;
  const char* Abase = (const char*)Wb + (size_t)(o0 + wid * 32 + (lane >> 2)) * rsA + chunkSwz;
  const char* Bbase = (const char*)X + ((size_t)b * N + n0 + wid * 32 + (lane >> 2)) * rsA + chunkSwz;
  size_t rstep16 = 16 * rsA;
  // read side: logical chunk = lane>>4, physical = (lane>>4) ^ ((lane>>1)&3)
  int kq = (((lane >> 4) ^ ((lane >> 1) & 3))) * 8;

  for (int k0 = 0; k0 < Cin; k0 += 32) {
    load_lds16(Abase + (size_t)k0 * 2, &As[(wid * 32) * 32]);
    load_lds16(Abase + (size_t)k0 * 2 + rstep16, &As[(wid * 32 + 16) * 32]);
    load_lds16(Bbase + (size_t)k0 * 2, &Bs[(wid * 32) * 32]);
    load_lds16(Bbase + (size_t)k0 * 2 + rstep16, &Bs[(wid * 32 + 16) * 32]);
    __syncthreads();
    bf16x8 af[4], bfv[4];
#pragma unroll
    for (int m = 0; m < 4; ++m)
      af[m] = *(const bf16x8*)&As[(wm * 64 + m * 16 + (lane & 15)) * 32 + kq];
#pragma unroll
    for (int nt = 0; nt < 4; ++nt)
      bfv[nt] = *(const bf16x8*)&Bs[(wn * 64 + nt * 16 + (lane & 15)) * 32 + kq];
#pragma unroll
    for (int m = 0; m < 4; ++m)
#pragma unroll
      for (int nt = 0; nt < 4; ++nt)
        acc[m][nt] = __builtin_amdgcn_mfma_f32_16x16x32_bf16(af[m], bfv[nt], acc[m][nt], 0, 0, 0);
    __syncthreads();
  }

  int col = lane & 15, rowq = lane >> 4;
#pragma unroll
  for (int m = 0; m < 4; ++m) {
    int ob = o0 + wm * 64 + m * 16 + rowq * 4;
    float4 bs = *(const float4*)&bias[ob];
#pragma unroll
    for (int nt = 0; nt < 4; ++nt) {
      int n = n0 + wn * 64 + nt * 16 + col;
      ushort4v v;
      v[0] = f2bf(acc[m][nt][0] + bs.x);
      v[1] = f2bf(acc[m][nt][1] + bs.y);
      v[2] = f2bf(acc[m][nt][2] + bs.z);
      v[3] = f2bf(acc[m][nt][3] + bs.w);
      *(ushort4v*)&Y[((size_t)b * N + n) * 256 + ob] = v;
    }
  }
}

// ---------------- per-channel stats over bf16 Y[b][n][256] ----------------
__global__ __launch_bounds__(256) void stats_kernel(const unsigned short* __restrict__ Y,
                                                    float* __restrict__ sum,
                                                    float* __restrict__ sumsq) {
  __shared__ float ls[8][256], lq[8][256];
  int tid = threadIdx.x, och = tid & 31, nt = tid >> 5;
  size_t r0 = (size_t)blockIdx.x * 256 + nt;
  float s[8], q[8];
#pragma unroll
  for (int j = 0; j < 8; ++j) { s[j] = 0.f; q[j] = 0.f; }
  for (int i = 0; i < 32; ++i) {
    ushort8v v = *(const ushort8v*)&Y[(r0 + (size_t)i * 8) * 256 + och * 8];
#pragma unroll
    for (int j = 0; j < 8; ++j) {
      float f = bf2f(v[j]);
      s[j] += f; q[j] += f * f;
    }
  }
#pragma unroll
  for (int j = 0; j < 8; ++j) { ls[nt][och * 8 + j] = s[j]; lq[nt][och * 8 + j] = q[j]; }
  __syncthreads();
  float ss = 0.f, qq = 0.f;
#pragma unroll
  for (int i = 0; i < 8; ++i) { ss += ls[i][tid]; qq += lq[i][tid]; }
  atomicAdd(&sum[tid], ss);
  atomicAdd(&sumsq[tid], qq);
}

__global__ void bnparam_kernel(const float* __restrict__ sum, const float* __restrict__ sumsq,
                               const float* __restrict__ gamma, const float* __restrict__ beta,
                               float* __restrict__ scale, float* __restrict__ shift) {
  int c = threadIdx.x;
  float m = sum[c] * (1.0f / CNT);
  float v = sumsq[c] * (1.0f / CNT) - m * m;
  float sc = gamma[c] * rsqrtf(v + 1e-5f);
  scale[c] = sc;
  shift[c] = beta[c] - m * sc;
}

// ---------------- BN+ReLU elementwise on [b][n][256] bf16 -> bf16 ----------------
__global__ __launch_bounds__(256) void bnrelu_kernel(const unsigned short* __restrict__ Y,
                                                     const float* __restrict__ scale,
                                                     const float* __restrict__ shift,
                                                     unsigned short* __restrict__ H) {
  size_t total = (size_t)B * N * 256 / 8;
  for (size_t i = (size_t)blockIdx.x * 256 + threadIdx.x; i < total;
       i += (size_t)gridDim.x * 256) {
    int ob = ((int)i & 31) * 8;
    float4 s0 = *(const float4*)&scale[ob];
    float4 s1 = *(const float4*)&scale[ob + 4];
    float4 h0 = *(const float4*)&shift[ob];
    float4 h1 = *(const float4*)&shift[ob + 4];
    ushort8v v = *(const ushort8v*)&Y[i * 8];
    ushort8v o;
    o[0] = f2bf(fmaxf(fmaf(bf2f(v[0]), s0.x, h0.x), 0.f));
    o[1] = f2bf(fmaxf(fmaf(bf2f(v[1]), s0.y, h0.y), 0.f));
    o[2] = f2bf(fmaxf(fmaf(bf2f(v[2]), s0.z, h0.z), 0.f));
    o[3] = f2bf(fmaxf(fmaf(bf2f(v[3]), s0.w, h0.w), 0.f));
    o[4] = f2bf(fmaxf(fmaf(bf2f(v[4]), s1.x, h1.x), 0.f));
    o[5] = f2bf(fmaxf(fmaf(bf2f(v[5]), s1.y, h1.y), 0.f));
    o[6] = f2bf(fmaxf(fmaf(bf2f(v[6]), s1.z, h1.z), 0.f));
    o[7] = f2bf(fmaxf(fmaf(bf2f(v[7]), s1.w, h1.w), 0.f));
    *(ushort8v*)&H[i * 8] = o;
  }
}

// ---------------- final: BN+ReLU + transpose [b][n][o] bf16 -> out [b][o][n] f32 ----------------
__global__ __launch_bounds__(256) void bnreluT_kernel(const unsigned short* __restrict__ Y,
                                                      const float* __restrict__ scale,
                                                      const float* __restrict__ shift,
                                                      float* __restrict__ out) {
  __shared__ float t[64][65];
  int n0 = blockIdx.x * 64, o0 = blockIdx.y * 64, b = blockIdx.z;
  int tid = threadIdx.x, r = tid >> 2, q = tid & 3;
  const unsigned short* yp = Y + ((size_t)b * N + n0 + r) * 256 + o0 + q * 16;
#pragma unroll
  for (int h = 0; h < 2; ++h) {
    ushort8v v = *(const ushort8v*)(yp + h * 8);
#pragma unroll
    for (int i = 0; i < 8; ++i) {
      int oc = q * 16 + h * 8 + i;
      float f = fmaxf(fmaf(bf2f(v[i]), scale[o0 + oc], shift[o0 + oc]), 0.f);
      t[oc][r] = f;
    }
  }
  __syncthreads();
  float* op = out + ((size_t)b * 256 + o0 + r) * N + n0 + q * 16;
#pragma unroll
  for (int i = 0; i < 4; ++i) {
    float4 v = make_float4(t[r][q * 16 + i * 4 + 0], t[r][q * 16 + i * 4 + 1],
                           t[r][q * 16 + i * 4 + 2], t[r][q * 16 + i * 4 + 3]);
    *(float4*)(op + i * 4) = v;
  }
}

extern "C" void kernel_launch(void* const* d_in, const int* in_sizes, int n_in,
                              void* d_out, int out_size, void* d_ws, size_t ws_size,
                              hipStream_t stream) {
  const float* xyz1 = (const float*)d_in[0];
  const float* xyz2 = (const float*)d_in[1];
  const float* points1 = (const float*)d_in[2];
  const float* points2 = (const float*)d_in[3];
  const float* w0 = (const float*)d_in[4];
  const float* b0 = (const float*)d_in[5];
  const float* g0 = (const float*)d_in[6];
  const float* be0 = (const float*)d_in[7];
  const float* w1 = (const float*)d_in[8];
  const float* b1 = (const float*)d_in[9];
  const float* g1 = (const float*)d_in[10];
  const float* be1 = (const float*)d_in[11];
  float* out = (float*)d_out;

  char* ws = (char*)d_ws;
  int* idxbuf = (int*)ws;              ws += (size_t)CNT * 3 * 4;      // 768KB
  float* wbuf = (float*)ws;            ws += (size_t)CNT * 3 * 4;      // 768KB
  float* stats = (float*)ws;           ws += (size_t)8 * 256 * 4;      // 8KB
  float* sum0 = stats, *sumsq0 = stats + 256;
  float* sum1 = stats + 512, *sumsq1 = stats + 768;
  float* scale0 = stats + 1024, *shift0 = stats + 1280;
  float* scale1 = stats + 1536, *shift1 = stats + 1792;
  unsigned short* w0b = (unsigned short*)ws;  ws += (size_t)C * CIN * 2;   // 256KB
  unsigned short* w1b = (unsigned short*)ws;  ws += (size_t)C * C * 2;     // 128KB
  unsigned short* p2t = (unsigned short*)ws;  ws += (size_t)B * S * 256 * 2;   // 8MB
  unsigned short* Xb = (unsigned short*)ws;   ws += (size_t)B * N * 512 * 2;   // 64MB
  unsigned short* Yb = (unsigned short*)ws;   ws += (size_t)B * N * 256 * 2;   // 32MB
  unsigned short* Hb = Xb;  // reuse Xb after GEMM0 consumed it

  hipMemsetAsync(stats, 0, 4 * 256 * 4, stream);
  convw_kernel<<<dim3((C * CIN + C * C) / 256), 256, 0, stream>>>(w0, w1, w0b, w1b);
  tconv_kernel<<<dim3(N / 64, 4, B), 256, 0, stream>>>(points1, Xb, N, 512, 0);
  tconv_kernel<<<dim3(S / 64, 4, B), 256, 0, stream>>>(points2, p2t, S, 256, 0);
  nn3_kernel<<<dim3(B * N / 32), 256, 0, stream>>>(xyz1, xyz2, idxbuf, wbuf);
  gather_kernel<<<dim3(B * N / 64), 256, 0, stream>>>(p2t, idxbuf, wbuf, Xb);
  gemm_kernel<<<dim3(N / 128, 2, B), 256, 0, stream>>>(Xb, w0b, b0, Yb, CIN);
  stats_kernel<<<dim3(CNT / 256), 256, 0, stream>>>(Yb, sum0, sumsq0);
  bnparam_kernel<<<1, 256, 0, stream>>>(sum0, sumsq0, g0, be0, scale0, shift0);
  bnrelu_kernel<<<dim3(2048), 256, 0, stream>>>(Yb, scale0, shift0, Hb);
  gemm_kernel<<<dim3(N / 128, 2, B), 256, 0, stream>>>(Hb, w1b, b1, Yb, C);
  stats_kernel<<<dim3(CNT / 256), 256, 0, stream>>>(Yb, sum1, sumsq1);
  bnparam_kernel<<<1, 256, 0, stream>>>(sum1, sumsq1, g1, be1, scale1, shift1);
  bnreluT_kernel<<<dim3(N / 64, 4, B), 256, 0, stream>>>(Yb, scale1, shift1, out);
}